// Round 1
// baseline (264.592 us; speedup 1.0000x reference)
//
#include <hip/hip_runtime.h>
#include <cstdint>
#include <cstddef>

using u32 = unsigned int;
using u64 = unsigned long long;

#define WROW 88        // u32 words per output-channel row in packed-weight table
#define EPSV 1e-5f

// ---------------------------------------------------------------------------
// Kernel 1: weight prep. One block per (co, conv). 256 threads = 256 in-chans.
// Produces per-co row: [72 packed bit-words (pos-major, 8 words/pos)]
//                      [9 wsum ints][pad][alpha, scale, shift as floats]
// bw = sign(w - mean_over(Cin,3,3))  (positive std-scale drops out; tau=1 ->
// clamp no-op). bn folded: scale = g/sqrt(v+eps), shift = b - m*g/sqrt(v+eps),
// computed with IEEE ops in the reference's exact order.
// ---------------------------------------------------------------------------
__global__ void prep_weights(const float* __restrict__ w1, const float* __restrict__ w2,
                             const float* __restrict__ a1, const float* __restrict__ g1,
                             const float* __restrict__ b1, const float* __restrict__ m1,
                             const float* __restrict__ v1,
                             const float* __restrict__ a2, const float* __restrict__ g2,
                             const float* __restrict__ b2, const float* __restrict__ m2,
                             const float* __restrict__ v2,
                             u32* __restrict__ PW)
{
    const int co   = blockIdx.x;
    const int conv = blockIdx.y;
    const int c    = threadIdx.x;          // input channel
    const float* w = conv ? w2 : w1;

    float wv[9];
    const float* wp = w + ((size_t)co * 256 + c) * 9;
    float s = 0.f;
#pragma unroll
    for (int p = 0; p < 9; ++p) { wv[p] = wp[p]; s += wv[p]; }

    __shared__ float red[256];
    __shared__ int   wcount[9];
    red[c] = s;
    if (c < 9) wcount[c] = 0;
    __syncthreads();
    for (int off = 128; off > 0; off >>= 1) {
        if (c < off) red[c] += red[c + off];
        __syncthreads();
    }
    const float mean = __fdiv_rn(red[0], 2304.0f);

    u32* row = PW + ((size_t)conv * 256 + co) * WROW;
    const int wave = c >> 6, lane = c & 63;
#pragma unroll
    for (int p = 0; p < 9; ++p) {
        u64 m = __ballot(wv[p] > mean);      // bit=1 <-> +1
        if (lane == 0) {
            row[p * 8 + wave * 2]     = (u32)m;
            row[p * 8 + wave * 2 + 1] = (u32)(m >> 32);
            atomicAdd(&wcount[p], __popcll(m));
        }
    }
    __syncthreads();
    if (c < 9) row[72 + c] = (u32)(2 * wcount[c] - 256);   // wsum per position
    if (c == 0) {
        const float alpha = conv ? a2[co] : a1[co];
        const float gamma = conv ? g2[co] : g1[co];
        const float beta  = conv ? b2[co] : b1[co];
        const float mu    = conv ? m2[co] : m1[co];
        const float var   = conv ? v2[co] : v1[co];
        const float sq    = __fsqrt_rn(__fadd_rn(var, EPSV));
        const float scale = __fdiv_rn(gamma, sq);
        const float shift = __fsub_rn(beta, __fdiv_rn(__fmul_rn(mu, gamma), sq));
        row[81] = __float_as_uint(alpha);
        row[82] = __float_as_uint(scale);
        row[83] = __float_as_uint(shift);
    }
}

// ---------------------------------------------------------------------------
// Kernel 2: binarize x -> packed bits. Layout A[n][pixel][j], j = chan/32.
// Block = (n, j), 1024 threads = pixels. Loads fully coalesced.
// ---------------------------------------------------------------------------
__global__ void binarize_x(const float* __restrict__ x, u32* __restrict__ A1)
{
    const int n = blockIdx.x >> 3;
    const int j = blockIdx.x & 7;
    const int p = threadIdx.x;              // pixel 0..1023
    const float* xp = x + (((size_t)n * 256 + j * 32) * 1024) + p;
    u32 bits = 0;
#pragma unroll
    for (int k = 0; k < 32; ++k) {
        float v = xp[(size_t)k * 1024];
        bits |= (v > 0.f ? 1u : 0u) << k;
    }
    A1[((size_t)n * 1024 + p) * 8 + j] = bits;
}

// ---------------------------------------------------------------------------
// Kernel 3/4: binary 3x3 conv via XOR+popcount.
// Grid: x = n*4 + rowtile (8 rows each), y = co-quarter (64 cos).
// 256 threads = 8 rows x 32 cols; each thread owns one pixel, loops 64 cos.
// Activations: 18 uint4 in registers (3x3 positions x 8 words).
// Weights: wave-uniform stream -> scalar/L1 path, no LDS needed.
// dot = 2304 - 2*popc + sum_{halo pos} wsum[pos].
// CONV==1: emit packed sign bits of bn(conv*alpha) (hardtanh preserves sign).
// CONV==2: fp32 epilogue: bn(conv*alpha) + x, clamp to [-1,1].
// ---------------------------------------------------------------------------
template<int CONV>
__global__ __launch_bounds__(256)
void conv_bin(const u32* __restrict__ A_in, const u32* __restrict__ PW,
              const float* __restrict__ X, float* __restrict__ OUT,
              u32* __restrict__ A_out)
{
    const int n   = blockIdx.x >> 2;
    const int rt  = blockIdx.x & 3;
    const int q   = blockIdx.y;
    const int tid = threadIdx.x;
    const int pr  = tid >> 5;       // row in tile 0..7
    const int cw  = tid & 31;       // col 0..31

    __shared__ u32 act[10 * 34 * 8];    // rows -1..8, cols -1..32, 8 words

    {   // cooperative staged load, halo zeroed. 680 uint4 total.
        const uint4* src = (const uint4*)A_in;
        uint4* dst = (uint4*)act;
        for (int s = tid; s < 680; s += 256) {
            int r    = s / 68;
            int rem  = s - r * 68;
            int c    = rem >> 1;
            int half = rem & 1;
            int ir = rt * 8 + r - 1;
            int ic = c - 1;
            uint4 v = make_uint4(0u, 0u, 0u, 0u);
            if ((unsigned)ir < 32u && (unsigned)ic < 32u)
                v = src[((size_t)n * 1024 + ir * 32 + ic) * 2 + half];
            dst[s] = v;
        }
    }
    __syncthreads();

    uint4 a[3][3][2];
#pragma unroll
    for (int dy = 0; dy < 3; ++dy)
#pragma unroll
        for (int dx = 0; dx < 3; ++dx)
#pragma unroll
            for (int h = 0; h < 2; ++h)
                a[dy][dx][h] = *(const uint4*)&act[(pr + dy) * 272 + (cw + dx) * 8 + h * 4];

    const int irow = rt * 8 + pr, icol = cw;
    u32 hm = 0;
#pragma unroll
    for (int dy = 0; dy < 3; ++dy)
#pragma unroll
        for (int dx = 0; dx < 3; ++dx) {
            int rr = irow + dy - 1, cc = icol + dx - 1;
            if (rr < 0 || rr >= 32 || cc < 0 || cc >= 32) hm |= 1u << (dy * 3 + dx);
        }

    u64 ow = 0;
    for (int i = 0; i < 64; ++i) {
        const int co = q * 64 + i;
        const u32* row = PW + ((size_t)((CONV == 2) ? 256 : 0) + co) * WROW;
        const uint4* row4 = (const uint4*)row;
        u32 s0 = 0, s1 = 0, s2 = 0, s3 = 0;
#pragma unroll
        for (int p = 0; p < 9; ++p) {
            const int dy = p / 3, dx = p % 3;
            uint4 wa = row4[p * 2];
            uint4 wb = row4[p * 2 + 1];
            s0 += __popc(a[dy][dx][0].x ^ wa.x);
            s1 += __popc(a[dy][dx][0].y ^ wa.y);
            s2 += __popc(a[dy][dx][0].z ^ wa.z);
            s3 += __popc(a[dy][dx][0].w ^ wa.w);
            s0 += __popc(a[dy][dx][1].x ^ wb.x);
            s1 += __popc(a[dy][dx][1].y ^ wb.y);
            s2 += __popc(a[dy][dx][1].z ^ wb.z);
            s3 += __popc(a[dy][dx][1].w ^ wb.w);
        }
        const int P = (int)(s0 + s1 + s2 + s3);
        int corr = 0;
        if (hm) {
#pragma unroll
            for (int p = 0; p < 9; ++p)
                if ((hm >> p) & 1) corr += (int)row[72 + p];
        }
        const int dot = 2304 - 2 * P + corr;

        const float alpha = __uint_as_float(row[81]);
        const float scale = __uint_as_float(row[82]);
        const float shift = __uint_as_float(row[83]);
        // match reference rounding: (conv*alpha) then *scale then +shift, no fma
        const float t = __fadd_rn(__fmul_rn(__fmul_rn((float)dot, alpha), scale), shift);

        if (CONV == 1) {
            ow |= (u64)(t > 0.f ? 1u : 0u) << i;
        } else {
            const size_t idx = (((size_t)n * 256 + co) * 1024) + (size_t)irow * 32 + icol;
            float y = __fadd_rn(t, X[idx]);
            y = fminf(1.0f, fmaxf(-1.0f, y));
            OUT[idx] = y;
        }
    }
    if (CONV == 1) {
        const size_t base = (((size_t)n * 1024) + (size_t)irow * 32 + icol) * 8 + q * 2;
        A_out[base]     = (u32)ow;
        A_out[base + 1] = (u32)(ow >> 32);
    }
}

// ---------------------------------------------------------------------------
extern "C" void kernel_launch(void* const* d_in, const int* in_sizes, int n_in,
                              void* d_out, int out_size, void* d_ws, size_t ws_size,
                              hipStream_t stream)
{
    const float* x   = (const float*)d_in[0];
    const float* w1  = (const float*)d_in[1];
    const float* al1 = (const float*)d_in[2];
    const float* g1  = (const float*)d_in[3];
    const float* b1  = (const float*)d_in[4];
    const float* m1  = (const float*)d_in[5];
    const float* v1  = (const float*)d_in[6];
    const float* w2  = (const float*)d_in[7];
    const float* al2 = (const float*)d_in[8];
    const float* g2  = (const float*)d_in[9];
    const float* b2  = (const float*)d_in[10];
    const float* m2  = (const float*)d_in[11];
    const float* v2  = (const float*)d_in[12];
    float* out = (float*)d_out;

    u32* PW = (u32*)d_ws;                               // 2*256*88*4 = 180 KB
    u32* A1 = (u32*)((char*)d_ws + (1u << 20));         // 2 MB packed sign(x)
    u32* A2 = (u32*)((char*)d_ws + 3u * (1u << 20));    // 2 MB packed layer-1 signs
    (void)ws_size; (void)in_sizes; (void)n_in; (void)out_size;

    prep_weights<<<dim3(256, 2), 256, 0, stream>>>(w1, w2, al1, g1, b1, m1, v1,
                                                   al2, g2, b2, m2, v2, PW);
    binarize_x<<<dim3(512), 1024, 0, stream>>>(x, A1);
    conv_bin<1><<<dim3(256, 4), 256, 0, stream>>>(A1, PW, nullptr, nullptr, A2);
    conv_bin<2><<<dim3(256, 4), 256, 0, stream>>>(A2, PW, x, out, nullptr);
}